// Round 5
// baseline (414.881 us; speedup 1.0000x reference)
//
#include <hip/hip_runtime.h>
#include <hip/hip_bf16.h>
#include <math.h>

#define D 2048
#define NH 16
#define KHD 8
#define HD 128
#define T_NOISE 1024
#define T_PAD 1024
#define MAX_KV 4096
#define SM_SCALE 0.08838834764831845f  /* 1/sqrt(128) */

typedef __attribute__((ext_vector_type(8))) short short8;
typedef __attribute__((ext_vector_type(4))) short short4v;
typedef __attribute__((ext_vector_type(4))) float f32x4;

__device__ __forceinline__ unsigned short f2bf(float f) {
    union { float f; unsigned u; } v; v.f = f;
    unsigned r = v.u + 0x7fff + ((v.u >> 16) & 1);   // round-nearest-even
    return (unsigned short)(r >> 16);
}

__device__ __forceinline__ void gload16(const void* g, void* l) {
    __builtin_amdgcn_global_load_lds(
        (const __attribute__((address_space(1))) unsigned int*)g,
        (__attribute__((address_space(3))) unsigned int*)l, 16, 0, 0);
}

// ---------------------------------------------------------------------------
// Concat + cast f32 -> bf16. 8 elems/thread. (unchanged)
// ---------------------------------------------------------------------------
__global__ __launch_bounds__(256)
void cast_concat(const float* __restrict__ A0, const float* __restrict__ A1,
                 short* __restrict__ out, int splitElems) {
    int i = (blockIdx.x * 256 + threadIdx.x) * 8;
    const float* src = (i < splitElems) ? (A0 + i) : (A1 + (i - splitElems));
    float4 f0 = *(const float4*)src;
    float4 f1 = *(const float4*)(src + 4);
    short8 s;
    s[0] = (short)f2bf(f0.x); s[1] = (short)f2bf(f0.y);
    s[2] = (short)f2bf(f0.z); s[3] = (short)f2bf(f0.w);
    s[4] = (short)f2bf(f1.x); s[5] = (short)f2bf(f1.y);
    s[6] = (short)f2bf(f1.z); s[7] = (short)f2bf(f1.w);
    *(short8*)(out + i) = s;
}

// ---------------------------------------------------------------------------
// Convert + transpose: W f32 [R][C] -> Wt bf16 [C][R]. (unchanged)
// ---------------------------------------------------------------------------
__global__ __launch_bounds__(256)
void conv_transpose(const float* __restrict__ W, short* __restrict__ Wt,
                    int R, int C) {
    __shared__ short t[64][72];
    int tid = threadIdx.x;
    int r0 = blockIdx.y * 64, c0 = blockIdx.x * 64;
    int rl = tid >> 4, cl4 = (tid & 15) * 4;
    #pragma unroll
    for (int j = 0; j < 4; ++j) {
        int r = rl + j * 16;
        float4 f = *(const float4*)(W + (size_t)(r0 + r) * C + c0 + cl4);
        t[cl4 + 0][r] = (short)f2bf(f.x);
        t[cl4 + 1][r] = (short)f2bf(f.y);
        t[cl4 + 2][r] = (short)f2bf(f.z);
        t[cl4 + 3][r] = (short)f2bf(f.w);
    }
    __syncthreads();
    #pragma unroll
    for (int j = 0; j < 2; ++j) {
        int idx = tid + j * 256;
        int cr = idx >> 3, rc8 = (idx & 7) * 8;
        *(short8*)(Wt + (size_t)(c0 + cr) * R + r0 + rc8) = *(const short8*)&t[cr][rc8];
    }
}

// ---------------------------------------------------------------------------
// bf16 MFMA GEMM (m97 structure). (unchanged)
// ---------------------------------------------------------------------------
__global__ __launch_bounds__(256)
void gemm_bf16(const short* __restrict__ A, const short* __restrict__ Bt,
               float* __restrict__ C0, float* __restrict__ C1,
               int csplit, int ldc, int K, int M) {
    __shared__ __align__(16) short As[128 * 32];
    __shared__ __align__(16) short Bs[128 * 32];
    const int tid = threadIdx.x;
    const int w = tid >> 6, lane = tid & 63;
    const int g = lane >> 4, li = lane & 15;
    const int wr = w >> 1, wc = w & 1;
    const int m0 = blockIdx.y * 128, n0 = blockIdx.x * 128;

    f32x4 acc[4][4];
    #pragma unroll
    for (int mi = 0; mi < 4; ++mi)
        #pragma unroll
        for (int ni = 0; ni < 4; ++ni) {
            acc[mi][ni][0] = 0.f; acc[mi][ni][1] = 0.f;
            acc[mi][ni][2] = 0.f; acc[mi][ni][3] = 0.f;
        }

    for (int k0 = 0; k0 < K; k0 += 32) {
        #pragma unroll
        for (int i = 0; i < 2; ++i) {
            int idx = i * 256 + w * 64 + lane;
            int row = idx >> 2, slot = idx & 3;
            gload16(A + (size_t)(m0 + row) * K + k0 + slot * 8,
                    (char*)As + (size_t)(i * 256 + w * 64) * 16);
            gload16(Bt + (size_t)(n0 + row) * K + k0 + slot * 8,
                    (char*)Bs + (size_t)(i * 256 + w * 64) * 16);
        }
        __syncthreads();
        short8 af[4], bf[4];
        #pragma unroll
        for (int mi = 0; mi < 4; ++mi)
            af[mi] = *(const short8*)&As[(wr * 64 + mi * 16 + li) * 32 + g * 8];
        #pragma unroll
        for (int ni = 0; ni < 4; ++ni)
            bf[ni] = *(const short8*)&Bs[(wc * 64 + ni * 16 + li) * 32 + g * 8];
        #pragma unroll
        for (int mi = 0; mi < 4; ++mi)
            #pragma unroll
            for (int ni = 0; ni < 4; ++ni)
                acc[mi][ni] = __builtin_amdgcn_mfma_f32_16x16x32_bf16(
                    af[mi], bf[ni], acc[mi][ni], 0, 0, 0);
        __syncthreads();
    }
    #pragma unroll
    for (int mi = 0; mi < 4; ++mi) {
        #pragma unroll
        for (int ni = 0; ni < 4; ++ni) {
            int n = n0 + wc * 64 + ni * 16 + li;
            float* cp; int cn;
            if (n < csplit) { cp = C0; cn = n; } else { cp = C1; cn = n - csplit; }
            #pragma unroll
            for (int r = 0; r < 4; ++r) {
                int m = m0 + wr * 64 + mi * 16 + 4 * g + r;
                cp[(size_t)m * ldc + cn] = acc[mi][ni][r];
            }
        }
    }
}

// ---------------------------------------------------------------------------
// Fused RMSNorm + RoPE, in place. (unchanged)
// ---------------------------------------------------------------------------
__global__ __launch_bounds__(128)
void rmsrope(float* __restrict__ x, int hpt,
             const int* __restrict__ posA, const int* __restrict__ posB,
             int splitT, const float* __restrict__ scale) {
    __shared__ float red[128];
    __shared__ float nrm[128];
    int row = blockIdx.x;
    int h = threadIdx.x;
    float v = x[(size_t)row * HD + h];
    red[h] = v * v;
    __syncthreads();
    #pragma unroll
    for (int off = 64; off > 0; off >>= 1) {
        if (h < off) red[h] += red[h + off];
        __syncthreads();
    }
    float inv = rsqrtf(red[0] * (1.0f / 128.0f) + 1e-6f);
    nrm[h] = v * inv * scale[h];
    __syncthreads();
    if (h < 64) {
        int t = row / hpt;
        int pos = (t < splitT) ? posA[t] : posB[t - splitT];
        float inv_freq = expf((float)h * (-13.815510557964274f / 64.0f));
        float ang = (float)pos * inv_freq;
        float c = cosf(ang), s = sinf(ang);
        float x1 = nrm[h], x2 = nrm[h + 64];
        x[(size_t)row * HD + h]      = x1 * c - x2 * s;
        x[(size_t)row * HD + h + 64] = x2 * c + x1 * s;
    }
}

// ---------------------------------------------------------------------------
// KV cache build. (unchanged)
// ---------------------------------------------------------------------------
__global__ __launch_bounds__(256)
void cache_scatter(const float* __restrict__ in_k, const float* __restrict__ in_v,
                   const float* __restrict__ k_rot, const float* __restrict__ v_new,
                   float* __restrict__ out_k, float* __restrict__ out_v,
                   const int* __restrict__ clp, const int* __restrict__ acp) {
    int cache_len = clp[0], actx = acp[0];
    int noise_start = cache_len + actx;
    int i = blockIdx.x * 256 + threadIdx.x;
    int n = i >> 17;
    int rem = i & 131071;
    int pos = rem >> 5;
    int h4 = (rem & 31) << 2;
    size_t co = ((size_t)(n * MAX_KV + pos)) * HD + h4;
    float4 kv, vv;
    if (pos >= noise_start && pos < noise_start + T_NOISE) {
        int srow = T_PAD + (pos - noise_start);
        size_t so = ((size_t)srow * KHD + (n >> 1)) * HD + h4;
        kv = *(const float4*)(k_rot + so);
        vv = *(const float4*)(v_new + so);
    } else if (pos >= cache_len && pos < cache_len + T_PAD) {
        int t = pos - cache_len;
        if (t < actx) {
            size_t so = ((size_t)t * KHD + (n >> 1)) * HD + h4;
            kv = *(const float4*)(k_rot + so);
            vv = *(const float4*)(v_new + so);
        } else {
            kv = make_float4(0.f, 0.f, 0.f, 0.f);
            vv = kv;
        }
    } else {
        kv = *(const float4*)(in_k + co);
        vv = *(const float4*)(in_v + co);
    }
    *(float4*)(out_k + co) = kv;
    *(float4*)(out_v + co) = vv;
}

// ---------------------------------------------------------------------------
// MFMA bf16 flash attention, 16 waves / block, in-block 4-way KV split.
// Wave w: kg = w>>2 (KV quarter), qw = w&3 (16-q-row group). Each iteration
// stages 4 KV tiles (one per quarter, 128 rows) double-buffered; group kg
// computes its quarter with private online-softmax state; final in-LDS merge.
//
// LDS (150 KB):
//   KQ(b,qq) = (b*4+qq)*8192          [0, 64K)   K tiles, row-swizzled
//   VQ(b,qq) = 65536+(b*4+qq)*8448    [64K,130K) V tiles, tr-read subtiles
//   PB(w)    = 133120+w*1280          [130K,150K) per-wave P
//   merge: Obuf f32[4][64][128] at 0, ml f32[4][64][2] at 131072 (post-barrier)
// ---------------------------------------------------------------------------
#define KQ(b, qq) (((b) * 4 + (qq)) * 8192)
#define VQ(b, qq) (65536 + ((b) * 4 + (qq)) * 8448)
#define PB(w) (133120 + (w) * 1280)

__device__ __forceinline__ short4v tr_read(unsigned addr) {
    short4v d;
    asm volatile("ds_read_b64_tr_b16 %0, %1" : "=v"(d) : "v"(addr));
    return d;
}

__global__ __launch_bounds__(1024, 4)
void attn_mfma(const float* __restrict__ qrot, const float* __restrict__ kc,
               const float* __restrict__ vc, short* __restrict__ aout,
               const int* __restrict__ clp, const int* __restrict__ acp) {
    __shared__ __align__(16) char smem[153600];
    const int tid  = threadIdx.x;
    const int w    = tid >> 6;       // 0..15
    const int lane = tid & 63;
    const int g    = lane >> 4;
    const int li   = lane & 15;
    const int qw   = w & 3;          // q sub-tile within the 64-row block
    const int kg   = w >> 2;         // KV quarter this wave computes
    const int head = blockIdx.y;
    const int q0   = blockIdx.x * 64;
    const int new_len = clp[0] + acp[0] + T_NOISE;
    const int ntiles  = (new_len + 31) >> 5;
    const int nt4     = (ntiles + 3) >> 2;    // tiles per quarter (<=32)

    const float* kbase = kc + (size_t)head * MAX_KV * HD;
    const float* vbase = vc + (size_t)head * MAX_KV * HD;

    // Q A-fragments (SM_SCALE folded in)
    short8 qf[4];
    {
        const int qidx = q0 + qw * 16 + li;
        const float* qp = qrot + ((size_t)qidx * NH + head) * HD;
        #pragma unroll
        for (int ks = 0; ks < 4; ++ks) {
            float4 f0 = *(const float4*)(qp + 32 * ks + 8 * g);
            float4 f1 = *(const float4*)(qp + 32 * ks + 8 * g + 4);
            short8 q;
            q[0] = (short)f2bf(f0.x * SM_SCALE); q[1] = (short)f2bf(f0.y * SM_SCALE);
            q[2] = (short)f2bf(f0.z * SM_SCALE); q[3] = (short)f2bf(f0.w * SM_SCALE);
            q[4] = (short)f2bf(f1.x * SM_SCALE); q[5] = (short)f2bf(f1.y * SM_SCALE);
            q[6] = (short)f2bf(f1.z * SM_SCALE); q[7] = (short)f2bf(f1.w * SM_SCALE);
            qf[ks] = q;
        }
    }

    f32x4 acc[8];
    #pragma unroll
    for (int n = 0; n < 8; ++n) { acc[n][0] = 0.f; acc[n][1] = 0.f; acc[n][2] = 0.f; acc[n][3] = 0.f; }
    float mrow[4], lrow[4];
    #pragma unroll
    for (int r = 0; r < 4; ++r) { mrow[r] = -INFINITY; lrow[r] = 0.f; }

    // staging coords: thread covers staged row sr (0..127) = quarter qq, row rr
    const int sr = tid >> 3;
    const int qq = sr >> 5;
    const int rr = sr & 31;
    const int sh = (tid & 7) << 4;
    const int ht = tid & 7;

    float4 kpre[4], vpre[4];
    {
        const int r0g = (qq * nt4) * 32 + rr;
        const float* kp = kbase + (size_t)r0g * HD + sh;
        const float* vp = vbase + (size_t)r0g * HD + sh;
        #pragma unroll
        for (int j = 0; j < 4; ++j) { kpre[j] = ((const float4*)kp)[j]; vpre[j] = ((const float4*)vp)[j]; }
    }

    for (int t = 0; t < nt4; ++t) {
        const int b = t & 1;
        // ---- stage tile t of quarter qq from prefetch regs ----
        {
            char* kb = smem + KQ(b, qq) + rr * 256;
            char* vb = smem + VQ(b, qq) + ht * 1056 + (rr >> 2) * 128 + (rr & 3) * 32;
            #pragma unroll
            for (int j = 0; j < 4; ++j) {
                float4 f = kpre[j];
                short4v s; s[0] = (short)f2bf(f.x); s[1] = (short)f2bf(f.y);
                           s[2] = (short)f2bf(f.z); s[3] = (short)f2bf(f.w);
                int colbyte = sh * 2 + 8 * j;
                *(short4v*)(kb + (((colbyte >> 4) ^ (rr & 7)) << 4) + (colbyte & 15)) = s;
                float4 fv = vpre[j];
                short4v sv; sv[0] = (short)f2bf(fv.x); sv[1] = (short)f2bf(fv.y);
                            sv[2] = (short)f2bf(fv.z); sv[3] = (short)f2bf(fv.w);
                *(short4v*)(vb + 8 * j) = sv;
            }
        }
        __syncthreads();
        // ---- prefetch tile t+1 of quarter qq ----
        if (t + 1 < nt4) {
            const int nr = (qq * nt4 + t + 1) * 32 + rr;
            const float* kp = kbase + (size_t)nr * HD + sh;
            const float* vp = vbase + (size_t)nr * HD + sh;
            #pragma unroll
            for (int j = 0; j < 4; ++j) { kpre[j] = ((const float4*)kp)[j]; vpre[j] = ((const float4*)vp)[j]; }
        }
        // ---- QK^T for quarter kg ----
        const int pos0 = (kg * nt4 + t) << 5;
        f32x4 s0, s1;
        s0[0]=0.f; s0[1]=0.f; s0[2]=0.f; s0[3]=0.f; s1 = s0;
        {
            const char* kbr = smem + KQ(b, kg);
            #pragma unroll
            for (int ks = 0; ks < 4; ++ks) {
                int slot = ((4 * ks + g) ^ (li & 7)) << 4;
                short8 k0 = *(const short8*)(kbr + li * 256 + slot);
                short8 k1 = *(const short8*)(kbr + (16 + li) * 256 + slot);
                s0 = __builtin_amdgcn_mfma_f32_16x16x32_bf16(qf[ks], k0, s0, 0, 0, 0);
                s1 = __builtin_amdgcn_mfma_f32_16x16x32_bf16(qf[ks], k1, s1, 0, 0, 0);
            }
        }
        if (pos0 + li >= new_len)      { s0[0] = -1e30f; s0[1] = -1e30f; s0[2] = -1e30f; s0[3] = -1e30f; }
        if (pos0 + li + 16 >= new_len) { s1[0] = -1e30f; s1[1] = -1e30f; s1[2] = -1e30f; s1[3] = -1e30f; }
        float p0v[4], p1v[4], alpha[4];
        #pragma unroll
        for (int r = 0; r < 4; ++r) {
            float mx = fmaxf(s0[r], s1[r]);
            #pragma unroll
            for (int off = 1; off < 16; off <<= 1) mx = fmaxf(mx, __shfl_xor(mx, off, 16));
            float mn = fmaxf(mrow[r], mx);
            alpha[r] = __expf(mrow[r] - mn);
            p0v[r] = __expf(s0[r] - mn);
            p1v[r] = __expf(s1[r] - mn);
            float rs = p0v[r] + p1v[r];
            #pragma unroll
            for (int off = 1; off < 16; off <<= 1) rs += __shfl_xor(rs, off, 16);
            lrow[r] = lrow[r] * alpha[r] + rs;
            mrow[r] = mn;
        }
        #pragma unroll
        for (int n = 0; n < 8; ++n)
            #pragma unroll
            for (int r = 0; r < 4; ++r) acc[n][r] *= alpha[r];
        // ---- P -> per-wave LDS (C-frag -> A-frag re-layout) ----
        {
            char* pb = smem + PB(w);
            #pragma unroll
            for (int r = 0; r < 4; ++r) {
                *(unsigned short*)(pb + (4 * g + r) * 80 + li * 2)        = f2bf(p0v[r]);
                *(unsigned short*)(pb + (4 * g + r) * 80 + (16 + li) * 2) = f2bf(p1v[r]);
            }
        }
        short8 pa = *(const short8*)(smem + PB(w) + li * 80 + g * 16);
        // ---- V B-fragments via hardware transpose read ----
        const unsigned vb0 = (unsigned)(size_t)(smem + VQ(b, kg)) + g * 256 + li * 8;
        short4v vt[16];
        #pragma unroll
        for (int h2 = 0; h2 < 8; ++h2) {
            vt[2 * h2]     = tr_read(vb0 + h2 * 1056);
            vt[2 * h2 + 1] = tr_read(vb0 + h2 * 1056 + 128);
        }
        asm volatile("s_waitcnt lgkmcnt(0)" ::: "memory");
        __builtin_amdgcn_sched_barrier(0);
        #pragma unroll
        for (int h2 = 0; h2 < 8; ++h2) {
            short8 vf = __builtin_shufflevector(vt[2 * h2], vt[2 * h2 + 1],
                                                0, 1, 2, 3, 4, 5, 6, 7);
            acc[h2] = __builtin_amdgcn_mfma_f32_16x16x32_bf16(pa, vf, acc[h2], 0, 0, 0);
        }
        __syncthreads();
    }

    // ---- cross-group merge (reuses KV LDS region; safe post-barrier) ----
    float* Ob = (float*)smem;                     // [4][64][128] f32
    float* ml = (float*)(smem + 131072);          // [4][64][2]  f32
    #pragma unroll
    for (int r = 0; r < 4; ++r) {
        const int row = qw * 16 + 4 * g + r;
        if (li == 0) {
            ml[(kg * 64 + row) * 2 + 0] = mrow[r];
            ml[(kg * 64 + row) * 2 + 1] = lrow[r];
        }
        #pragma unroll
        for (int n = 0; n < 8; ++n)
            Ob[kg * 8192 + row * 128 + 16 * n + li] = acc[n][r];
    }
    __syncthreads();
    {
        const int rr2 = tid >> 4;                 // 0..63
        const int cb  = (tid & 15) * 8;           // col base
        float mg[4], lg[4];
        float mstar = -INFINITY;
        #pragma unroll
        for (int g2 = 0; g2 < 4; ++g2) {
            mg[g2] = ml[(g2 * 64 + rr2) * 2 + 0];
            lg[g2] = ml[(g2 * 64 + rr2) * 2 + 1];
            mstar = fmaxf(mstar, mg[g2]);
        }
        float cg[4], lstar = 0.f;
        #pragma unroll
        for (int g2 = 0; g2 < 4; ++g2) { cg[g2] = __expf(mg[g2] - mstar); lstar += lg[g2] * cg[g2]; }
        const float inv = 1.0f / lstar;
        float o[8] = {};
        #pragma unroll
        for (int g2 = 0; g2 < 4; ++g2) {
            f32x4 a = *(const f32x4*)&Ob[g2 * 8192 + rr2 * 128 + cb];
            f32x4 bq = *(const f32x4*)&Ob[g2 * 8192 + rr2 * 128 + cb + 4];
            o[0] += a[0] * cg[g2]; o[1] += a[1] * cg[g2];
            o[2] += a[2] * cg[g2]; o[3] += a[3] * cg[g2];
            o[4] += bq[0] * cg[g2]; o[5] += bq[1] * cg[g2];
            o[6] += bq[2] * cg[g2]; o[7] += bq[3] * cg[g2];
        }
        short8 o8;
        #pragma unroll
        for (int j = 0; j < 8; ++j) o8[j] = (short)f2bf(o[j] * inv);
        *(short8*)(aout + ((size_t)(q0 + rr2) * NH + head) * HD + cb) = o8;
    }
}

// ---------------------------------------------------------------------------
extern "C" void kernel_launch(void* const* d_in, const int* in_sizes, int n_in,
                              void* d_out, int out_size, void* d_ws, size_t ws_size,
                              hipStream_t stream) {
    const float* x_noise       = (const float*)d_in[0];
    const float* target_hidden = (const float*)d_in[1];
    const int*   noise_pos     = (const int*)d_in[2];
    const int*   ctx_pos       = (const int*)d_in[3];
    const float* in_k          = (const float*)d_in[4];
    const float* in_v          = (const float*)d_in[5];
    const int*   clp           = (const int*)d_in[6];
    const int*   acp           = (const int*)d_in[7];
    const float* Wq            = (const float*)d_in[8];
    const float* Wk            = (const float*)d_in[9];
    const float* Wv            = (const float*)d_in[10];
    const float* Wo            = (const float*)d_in[11];
    const float* q_scale       = (const float*)d_in[12];
    const float* k_scale       = (const float*)d_in[13];

    float* out   = (float*)d_out;
    float* out_k = out + (size_t)T_NOISE * D;
    float* out_v = out_k + (size_t)NH * MAX_KV * HD;

    float* ws    = (float*)d_ws;
    float* q_tmp = ws;                            // [0, 2M) floats
    float* k_tmp = ws + 2u * 1024 * 1024;         // [2M, 4M)
    float* v_tmp = ws + 4u * 1024 * 1024;         // [4M, 6M)
    short* xbf   = (short*)(ws + 6u * 1024 * 1024);   // [6M, 8M)
    short* a_bf  = xbf;                           // overlays xbf (dead after KV GEMM)
    short* wq_t  = (short*)(ws + 8u * 1024 * 1024);   // [8M, 10M)
    short* wk_t  = (short*)(ws + 10u * 1024 * 1024);  // [10M, 11M)
    short* wv_t  = wk_t + 1024 * 2048;                // [11M, 12M)
    short* wo_t  = wk_t;                          // overlays wk/wv (dead after KV GEMM)

    dim3 blk(256);
    cast_concat<<<2048, blk, 0, stream>>>(target_hidden, x_noise, xbf, 1024 * 2048);
    conv_transpose<<<dim3(32, 32), blk, 0, stream>>>(Wq, wq_t, 2048, 2048);
    conv_transpose<<<dim3(16, 32), blk, 0, stream>>>(Wk, wk_t, 2048, 1024);
    conv_transpose<<<dim3(16, 32), blk, 0, stream>>>(Wv, wv_t, 2048, 1024);
    gemm_bf16<<<dim3(16, 8), blk, 0, stream>>>(
        xbf + (size_t)1024 * 2048, wq_t, q_tmp, q_tmp, 2048, 2048, 2048, 1024);
    gemm_bf16<<<dim3(16, 16), blk, 0, stream>>>(
        xbf, wk_t, k_tmp, v_tmp, 1024, 1024, 2048, 2048);
    conv_transpose<<<dim3(32, 32), blk, 0, stream>>>(Wo, wo_t, 2048, 2048);
    rmsrope<<<1024 * 16, 128, 0, stream>>>(q_tmp, NH, noise_pos, noise_pos, 2048, q_scale);
    rmsrope<<<2048 * 8, 128, 0, stream>>>(k_tmp, KHD, ctx_pos, noise_pos, 1024, k_scale);
    cache_scatter<<<8192, 256, 0, stream>>>(in_k, in_v, k_tmp, v_tmp, out_k, out_v, clp, acp);
    attn_mfma<<<dim3(16, 16), 1024, 0, stream>>>(q_tmp, out_k, out_v, a_bf, clp, acp);
    gemm_bf16<<<dim3(16, 8), blk, 0, stream>>>(
        a_bf, wo_t, out, out, 2048, 2048, 2048, 1024);
}

// Round 6
// 301.643 us; speedup vs baseline: 1.3754x; 1.3754x over previous
//
#include <hip/hip_runtime.h>
#include <hip/hip_bf16.h>
#include <math.h>

#define D 2048
#define NH 16
#define KHD 8
#define HD 128
#define T_NOISE 1024
#define T_PAD 1024
#define MAX_KV 4096
#define SM_SCALE 0.08838834764831845f  /* 1/sqrt(128) */

typedef __attribute__((ext_vector_type(8))) short short8;
typedef __attribute__((ext_vector_type(4))) short short4v;
typedef __attribute__((ext_vector_type(4))) float f32x4;

__device__ __forceinline__ unsigned short f2bf(float f) {
    union { float f; unsigned u; } v; v.f = f;
    unsigned r = v.u + 0x7fff + ((v.u >> 16) & 1);   // round-nearest-even
    return (unsigned short)(r >> 16);
}
__device__ __forceinline__ float bf2f(short s) {
    union { unsigned u; float f; } v; v.u = ((unsigned)(unsigned short)s) << 16;
    return v.f;
}
__device__ __forceinline__ void gload16(const void* g, void* l) {
    __builtin_amdgcn_global_load_lds(
        (const __attribute__((address_space(1))) unsigned int*)g,
        (__attribute__((address_space(3))) unsigned int*)l, 16, 0, 0);
}

// ---------------------------------------------------------------------------
// Concat + cast f32 -> bf16. (unchanged)
// ---------------------------------------------------------------------------
__global__ __launch_bounds__(256)
void cast_concat(const float* __restrict__ A0, const float* __restrict__ A1,
                 short* __restrict__ out, int splitElems) {
    int i = (blockIdx.x * 256 + threadIdx.x) * 8;
    const float* src = (i < splitElems) ? (A0 + i) : (A1 + (i - splitElems));
    float4 f0 = *(const float4*)src;
    float4 f1 = *(const float4*)(src + 4);
    short8 s;
    s[0] = (short)f2bf(f0.x); s[1] = (short)f2bf(f0.y);
    s[2] = (short)f2bf(f0.z); s[3] = (short)f2bf(f0.w);
    s[4] = (short)f2bf(f1.x); s[5] = (short)f2bf(f1.y);
    s[6] = (short)f2bf(f1.z); s[7] = (short)f2bf(f1.w);
    *(short8*)(out + i) = s;
}

// ---------------------------------------------------------------------------
// Convert + transpose: W f32 [R][C] -> Wt bf16 [C][R]. (unchanged)
// ---------------------------------------------------------------------------
__global__ __launch_bounds__(256)
void conv_transpose(const float* __restrict__ W, short* __restrict__ Wt,
                    int R, int C) {
    __shared__ short t[64][72];
    int tid = threadIdx.x;
    int r0 = blockIdx.y * 64, c0 = blockIdx.x * 64;
    int rl = tid >> 4, cl4 = (tid & 15) * 4;
    #pragma unroll
    for (int j = 0; j < 4; ++j) {
        int r = rl + j * 16;
        float4 f = *(const float4*)(W + (size_t)(r0 + r) * C + c0 + cl4);
        t[cl4 + 0][r] = (short)f2bf(f.x);
        t[cl4 + 1][r] = (short)f2bf(f.y);
        t[cl4 + 2][r] = (short)f2bf(f.z);
        t[cl4 + 3][r] = (short)f2bf(f.w);
    }
    __syncthreads();
    #pragma unroll
    for (int j = 0; j < 2; ++j) {
        int idx = tid + j * 256;
        int cr = idx >> 3, rc8 = (idx & 7) * 8;
        *(short8*)(Wt + (size_t)(c0 + cr) * R + r0 + rc8) = *(const short8*)&t[cr][rc8];
    }
}

// ---------------------------------------------------------------------------
// bf16 MFMA GEMM, f32 output. (unchanged, m97 structure)
// ---------------------------------------------------------------------------
__global__ __launch_bounds__(256)
void gemm_bf16(const short* __restrict__ A, const short* __restrict__ Bt,
               float* __restrict__ C0, float* __restrict__ C1,
               int csplit, int ldc, int K, int M) {
    __shared__ __align__(16) short As[128 * 32];
    __shared__ __align__(16) short Bs[128 * 32];
    const int tid = threadIdx.x;
    const int w = tid >> 6, lane = tid & 63;
    const int g = lane >> 4, li = lane & 15;
    const int wr = w >> 1, wc = w & 1;
    const int m0 = blockIdx.y * 128, n0 = blockIdx.x * 128;

    f32x4 acc[4][4];
    #pragma unroll
    for (int mi = 0; mi < 4; ++mi)
        #pragma unroll
        for (int ni = 0; ni < 4; ++ni) {
            acc[mi][ni][0] = 0.f; acc[mi][ni][1] = 0.f;
            acc[mi][ni][2] = 0.f; acc[mi][ni][3] = 0.f;
        }

    for (int k0 = 0; k0 < K; k0 += 32) {
        #pragma unroll
        for (int i = 0; i < 2; ++i) {
            int idx = i * 256 + w * 64 + lane;
            int row = idx >> 2, slot = idx & 3;
            gload16(A + (size_t)(m0 + row) * K + k0 + slot * 8,
                    (char*)As + (size_t)(i * 256 + w * 64) * 16);
            gload16(Bt + (size_t)(n0 + row) * K + k0 + slot * 8,
                    (char*)Bs + (size_t)(i * 256 + w * 64) * 16);
        }
        __syncthreads();
        short8 af[4], bf[4];
        #pragma unroll
        for (int mi = 0; mi < 4; ++mi)
            af[mi] = *(const short8*)&As[(wr * 64 + mi * 16 + li) * 32 + g * 8];
        #pragma unroll
        for (int ni = 0; ni < 4; ++ni)
            bf[ni] = *(const short8*)&Bs[(wc * 64 + ni * 16 + li) * 32 + g * 8];
        #pragma unroll
        for (int mi = 0; mi < 4; ++mi)
            #pragma unroll
            for (int ni = 0; ni < 4; ++ni)
                acc[mi][ni] = __builtin_amdgcn_mfma_f32_16x16x32_bf16(
                    af[mi], bf[ni], acc[mi][ni], 0, 0, 0);
        __syncthreads();
    }
    #pragma unroll
    for (int mi = 0; mi < 4; ++mi) {
        #pragma unroll
        for (int ni = 0; ni < 4; ++ni) {
            int n = n0 + wc * 64 + ni * 16 + li;
            float* cp; int cn;
            if (n < csplit) { cp = C0; cn = n; } else { cp = C1; cn = n - csplit; }
            #pragma unroll
            for (int r = 0; r < 4; ++r) {
                int m = m0 + wr * 64 + mi * 16 + 4 * g + r;
                cp[(size_t)m * ldc + cn] = acc[mi][ni][r];
            }
        }
    }
}

// ---------------------------------------------------------------------------
// Same GEMM with bf16 output (for the KV projection).
// ---------------------------------------------------------------------------
__global__ __launch_bounds__(256)
void gemm_bf16_bo(const short* __restrict__ A, const short* __restrict__ Bt,
                  short* __restrict__ C0, short* __restrict__ C1,
                  int csplit, int ldc, int K, int M) {
    __shared__ __align__(16) short As[128 * 32];
    __shared__ __align__(16) short Bs[128 * 32];
    const int tid = threadIdx.x;
    const int w = tid >> 6, lane = tid & 63;
    const int g = lane >> 4, li = lane & 15;
    const int wr = w >> 1, wc = w & 1;
    const int m0 = blockIdx.y * 128, n0 = blockIdx.x * 128;

    f32x4 acc[4][4];
    #pragma unroll
    for (int mi = 0; mi < 4; ++mi)
        #pragma unroll
        for (int ni = 0; ni < 4; ++ni) {
            acc[mi][ni][0] = 0.f; acc[mi][ni][1] = 0.f;
            acc[mi][ni][2] = 0.f; acc[mi][ni][3] = 0.f;
        }

    for (int k0 = 0; k0 < K; k0 += 32) {
        #pragma unroll
        for (int i = 0; i < 2; ++i) {
            int idx = i * 256 + w * 64 + lane;
            int row = idx >> 2, slot = idx & 3;
            gload16(A + (size_t)(m0 + row) * K + k0 + slot * 8,
                    (char*)As + (size_t)(i * 256 + w * 64) * 16);
            gload16(Bt + (size_t)(n0 + row) * K + k0 + slot * 8,
                    (char*)Bs + (size_t)(i * 256 + w * 64) * 16);
        }
        __syncthreads();
        short8 af[4], bf[4];
        #pragma unroll
        for (int mi = 0; mi < 4; ++mi)
            af[mi] = *(const short8*)&As[(wr * 64 + mi * 16 + li) * 32 + g * 8];
        #pragma unroll
        for (int ni = 0; ni < 4; ++ni)
            bf[ni] = *(const short8*)&Bs[(wc * 64 + ni * 16 + li) * 32 + g * 8];
        #pragma unroll
        for (int mi = 0; mi < 4; ++mi)
            #pragma unroll
            for (int ni = 0; ni < 4; ++ni)
                acc[mi][ni] = __builtin_amdgcn_mfma_f32_16x16x32_bf16(
                    af[mi], bf[ni], acc[mi][ni], 0, 0, 0);
        __syncthreads();
    }
    #pragma unroll
    for (int mi = 0; mi < 4; ++mi) {
        #pragma unroll
        for (int ni = 0; ni < 4; ++ni) {
            int n = n0 + wc * 64 + ni * 16 + li;
            short* cp; int cn;
            if (n < csplit) { cp = C0; cn = n; } else { cp = C1; cn = n - csplit; }
            #pragma unroll
            for (int r = 0; r < 4; ++r) {
                int m = m0 + wr * 64 + mi * 16 + 4 * g + r;
                cp[(size_t)m * ldc + cn] = (short)f2bf(acc[mi][ni][r]);
            }
        }
    }
}

// ---------------------------------------------------------------------------
// Fused RMSNorm + RoPE, f32 in-place (Q path). (unchanged)
// ---------------------------------------------------------------------------
__global__ __launch_bounds__(128)
void rmsrope(float* __restrict__ x, int hpt,
             const int* __restrict__ posA, const int* __restrict__ posB,
             int splitT, const float* __restrict__ scale) {
    __shared__ float red[128];
    __shared__ float nrm[128];
    int row = blockIdx.x;
    int h = threadIdx.x;
    float v = x[(size_t)row * HD + h];
    red[h] = v * v;
    __syncthreads();
    #pragma unroll
    for (int off = 64; off > 0; off >>= 1) {
        if (h < off) red[h] += red[h + off];
        __syncthreads();
    }
    float inv = rsqrtf(red[0] * (1.0f / 128.0f) + 1e-6f);
    nrm[h] = v * inv * scale[h];
    __syncthreads();
    if (h < 64) {
        int t = row / hpt;
        int pos = (t < splitT) ? posA[t] : posB[t - splitT];
        float inv_freq = expf((float)h * (-13.815510557964274f / 64.0f));
        float ang = (float)pos * inv_freq;
        float c = cosf(ang), s = sinf(ang);
        float x1 = nrm[h], x2 = nrm[h + 64];
        x[(size_t)row * HD + h]      = x1 * c - x2 * s;
        x[(size_t)row * HD + h + 64] = x2 * c + x1 * s;
    }
}

// ---------------------------------------------------------------------------
// Fused RMSNorm + RoPE, bf16 in-place (K path).
// ---------------------------------------------------------------------------
__global__ __launch_bounds__(128)
void rmsrope_bf(short* __restrict__ x, int hpt,
                const int* __restrict__ posA, const int* __restrict__ posB,
                int splitT, const float* __restrict__ scale) {
    __shared__ float red[128];
    __shared__ float nrm[128];
    int row = blockIdx.x;
    int h = threadIdx.x;
    float v = bf2f(x[(size_t)row * HD + h]);
    red[h] = v * v;
    __syncthreads();
    #pragma unroll
    for (int off = 64; off > 0; off >>= 1) {
        if (h < off) red[h] += red[h + off];
        __syncthreads();
    }
    float inv = rsqrtf(red[0] * (1.0f / 128.0f) + 1e-6f);
    nrm[h] = v * inv * scale[h];
    __syncthreads();
    if (h < 64) {
        int t = row / hpt;
        int pos = (t < splitT) ? posA[t] : posB[t - splitT];
        float inv_freq = expf((float)h * (-13.815510557964274f / 64.0f));
        float ang = (float)pos * inv_freq;
        float c = cosf(ang), s = sinf(ang);
        float x1 = nrm[h], x2 = nrm[h + 64];
        x[(size_t)row * HD + h]      = (short)f2bf(x1 * c - x2 * s);
        x[(size_t)row * HD + h + 64] = (short)f2bf(x2 * c + x1 * s);
    }
}

// ---------------------------------------------------------------------------
// Cache build: writes f32 output caches AND bf16 attention copies.
// New region [cache_len, new_len) comes from k_tmpb/v_tmpb (bf16, GQA-expand
// n -> n>>1); zero rows are fully shadowed by the noise region so never
// materialize. Old region copies in_k/in_v f32 and converts to bf16.
// One thread per 8 elements: 16*4096*16 threads.
// ---------------------------------------------------------------------------
__global__ __launch_bounds__(256)
void cache_scatter2(const float* __restrict__ in_k, const float* __restrict__ in_v,
                    const short* __restrict__ k_tmpb, const short* __restrict__ v_tmpb,
                    float* __restrict__ out_k, float* __restrict__ out_v,
                    short* __restrict__ kbf, short* __restrict__ vbf,
                    const int* __restrict__ clp, const int* __restrict__ acp) {
    const int cache_len = clp[0], actx = acp[0];
    const int noise_start = cache_len + actx;
    const int new_len = noise_start + T_NOISE;
    int i = blockIdx.x * 256 + threadIdx.x;
    int n = i >> 16;
    int rem = i & 65535;
    int pos = rem >> 4;
    int h8 = (rem & 15) << 3;
    size_t co = ((size_t)(n * MAX_KV + pos)) * HD + h8;
    short8 ks8, vs8;
    if (pos >= cache_len && pos < new_len) {
        int tkn = (pos < noise_start) ? (pos - cache_len) : (T_PAD + (pos - noise_start));
        size_t so = ((size_t)(tkn * KHD + (n >> 1))) * HD + h8;
        ks8 = *(const short8*)(k_tmpb + so);
        vs8 = *(const short8*)(v_tmpb + so);
        float4 a, b;
        a.x = bf2f(ks8[0]); a.y = bf2f(ks8[1]); a.z = bf2f(ks8[2]); a.w = bf2f(ks8[3]);
        b.x = bf2f(ks8[4]); b.y = bf2f(ks8[5]); b.z = bf2f(ks8[6]); b.w = bf2f(ks8[7]);
        *(float4*)(out_k + co) = a; *(float4*)(out_k + co + 4) = b;
        a.x = bf2f(vs8[0]); a.y = bf2f(vs8[1]); a.z = bf2f(vs8[2]); a.w = bf2f(vs8[3]);
        b.x = bf2f(vs8[4]); b.y = bf2f(vs8[5]); b.z = bf2f(vs8[6]); b.w = bf2f(vs8[7]);
        *(float4*)(out_v + co) = a; *(float4*)(out_v + co + 4) = b;
    } else {
        float4 ka = *(const float4*)(in_k + co);
        float4 kb = *(const float4*)(in_k + co + 4);
        float4 va = *(const float4*)(in_v + co);
        float4 vb = *(const float4*)(in_v + co + 4);
        *(float4*)(out_k + co) = ka; *(float4*)(out_k + co + 4) = kb;
        *(float4*)(out_v + co) = va; *(float4*)(out_v + co + 4) = vb;
        ks8[0] = (short)f2bf(ka.x); ks8[1] = (short)f2bf(ka.y);
        ks8[2] = (short)f2bf(ka.z); ks8[3] = (short)f2bf(ka.w);
        ks8[4] = (short)f2bf(kb.x); ks8[5] = (short)f2bf(kb.y);
        ks8[6] = (short)f2bf(kb.z); ks8[7] = (short)f2bf(kb.w);
        vs8[0] = (short)f2bf(va.x); vs8[1] = (short)f2bf(va.y);
        vs8[2] = (short)f2bf(va.z); vs8[3] = (short)f2bf(va.w);
        vs8[4] = (short)f2bf(vb.x); vs8[5] = (short)f2bf(vb.y);
        vs8[6] = (short)f2bf(vb.z); vs8[7] = (short)f2bf(vb.w);
    }
    *(short8*)(kbf + co) = ks8;
    *(short8*)(vbf + co) = vs8;
}

// ---------------------------------------------------------------------------
// MFMA bf16 flash attention. 16 waves, 4-way KV split (round-5 schedule) but:
//  - KV read from bf16 caches via global_load_lds (no reg staging / f2bf)
//  - K swizzle pre-applied to the per-lane GLOBAL source (rule 21)
//  - XCD-clustered block decode: heads {2x,2x+1} on XCD x -> KV L2-resident
// ---------------------------------------------------------------------------
#define KQ(b, qq) (((b) * 4 + (qq)) * 8192)
#define VQ(b, qq) (65536 + ((b) * 4 + (qq)) * 8448)
#define PB(w) (133120 + (w) * 1280)

__device__ __forceinline__ short4v tr_read(unsigned addr) {
    short4v d;
    asm volatile("ds_read_b64_tr_b16 %0, %1" : "=v"(d) : "v"(addr));
    return d;
}

__global__ __launch_bounds__(1024, 4)
void attn_mfma(const float* __restrict__ qrot, const short* __restrict__ kbf,
               const short* __restrict__ vbf, short* __restrict__ aout,
               const int* __restrict__ clp, const int* __restrict__ acp) {
    __shared__ __align__(16) char smem[153600];
    const int tid  = threadIdx.x;
    const int w    = tid >> 6;       // 0..15
    const int lane = tid & 63;
    const int g    = lane >> 4;
    const int li   = lane & 15;
    const int qw   = w & 3;          // q sub-tile (compute role)
    const int kg   = w >> 2;         // KV quarter (compute role)
    const int sq   = w & 3;          // quarter staged by this wave
    const int p    = w >> 2;         // staging part: 0,1=K halves; 2,3=V halves
    const int bid  = blockIdx.x;
    const int head = 2 * (bid & 7) + ((bid >> 3) >> 4);   // XCD-clustered
    const int q0   = ((bid >> 3) & 15) * 64;
    const int new_len = clp[0] + acp[0] + T_NOISE;
    const int ntiles  = (new_len + 31) >> 5;
    const int nt4     = (ntiles + 3) >> 2;

    const short* kb_g = kbf + (size_t)head * MAX_KV * HD;
    const short* vb_g = vbf + (size_t)head * MAX_KV * HD;

    // Q A-fragments (SM_SCALE folded in)
    short8 qf[4];
    {
        const int qidx = q0 + qw * 16 + li;
        const float* qp = qrot + ((size_t)qidx * NH + head) * HD;
        #pragma unroll
        for (int ks = 0; ks < 4; ++ks) {
            float4 f0 = *(const float4*)(qp + 32 * ks + 8 * g);
            float4 f1 = *(const float4*)(qp + 32 * ks + 8 * g + 4);
            short8 q;
            q[0] = (short)f2bf(f0.x * SM_SCALE); q[1] = (short)f2bf(f0.y * SM_SCALE);
            q[2] = (short)f2bf(f0.z * SM_SCALE); q[3] = (short)f2bf(f0.w * SM_SCALE);
            q[4] = (short)f2bf(f1.x * SM_SCALE); q[5] = (short)f2bf(f1.y * SM_SCALE);
            q[6] = (short)f2bf(f1.z * SM_SCALE); q[7] = (short)f2bf(f1.w * SM_SCALE);
            qf[ks] = q;
        }
    }

    f32x4 acc[8];
    #pragma unroll
    for (int n = 0; n < 8; ++n) { acc[n][0] = 0.f; acc[n][1] = 0.f; acc[n][2] = 0.f; acc[n][3] = 0.f; }
    float mrow[4], lrow[4];
    #pragma unroll
    for (int r = 0; r < 4; ++r) { mrow[r] = -INFINITY; lrow[r] = 0.f; }

    // per-lane staging constants
    const int krow16 = lane >> 4;              // K: row within 4-row group
    const int kchunkS = lane & 15;             // K: 16B slot before swizzle
    const int vrloc = 4 * (lane >> 3) + ((lane >> 1) & 3);   // V: row in tile
    const int vcof  = (lane & 1) * 8;          // V: col offset (elems)

    auto STAGE = [&](int tt, int bb) {
        const int base = (sq * nt4 + tt) * 32;
        if (p < 2) {
            #pragma unroll
            for (int i2 = 0; i2 < 4; ++i2) {
                const int i = p * 4 + i2;
                const int rloc = 4 * i + krow16;
                const int chunk = kchunkS ^ (rloc & 7);
                gload16(kb_g + ((size_t)(base + rloc) << 7) + chunk * 8,
                        smem + KQ(bb, sq) + i * 1024);
            }
        } else {
            #pragma unroll
            for (int i2 = 0; i2 < 4; ++i2) {
                const int ht = (p - 2) * 4 + i2;
                gload16(vb_g + ((size_t)(base + vrloc) << 7) + ht * 16 + vcof,
                        smem + VQ(bb, sq) + ht * 1056);
            }
        }
    };

    STAGE(0, 0);
    __syncthreads();

    for (int t = 0; t < nt4; ++t) {
        const int b = t & 1;
        if (t + 1 < nt4) STAGE(t + 1, b ^ 1);   // async; overlaps compute
        // ---- QK^T for quarter kg ----
        const int pos0 = (kg * nt4 + t) << 5;
        f32x4 s0, s1;
        s0[0]=0.f; s0[1]=0.f; s0[2]=0.f; s0[3]=0.f; s1 = s0;
        {
            const char* kbr = smem + KQ(b, kg);
            #pragma unroll
            for (int ks = 0; ks < 4; ++ks) {
                int slot = ((4 * ks + g) ^ (li & 7)) << 4;
                short8 k0 = *(const short8*)(kbr + li * 256 + slot);
                short8 k1 = *(const short8*)(kbr + (16 + li) * 256 + slot);
                s0 = __builtin_amdgcn_mfma_f32_16x16x32_bf16(qf[ks], k0, s0, 0, 0, 0);
                s1 = __builtin_amdgcn_mfma_f32_16x16x32_bf16(qf[ks], k1, s1, 0, 0, 0);
            }
        }
        if (pos0 + li >= new_len)      { s0[0] = -1e30f; s0[1] = -1e30f; s0[2] = -1e30f; s0[3] = -1e30f; }
        if (pos0 + li + 16 >= new_len) { s1[0] = -1e30f; s1[1] = -1e30f; s1[2] = -1e30f; s1[3] = -1e30f; }
        float p0v[4], p1v[4], alpha[4];
        #pragma unroll
        for (int r = 0; r < 4; ++r) {
            float mx = fmaxf(s0[r], s1[r]);
            #pragma unroll
            for (int off = 1; off < 16; off <<= 1) mx = fmaxf(mx, __shfl_xor(mx, off, 16));
            float mn = fmaxf(mrow[r], mx);
            alpha[r] = __expf(mrow[r] - mn);
            p0v[r] = __expf(s0[r] - mn);
            p1v[r] = __expf(s1[r] - mn);
            float rs = p0v[r] + p1v[r];
            #pragma unroll
            for (int off = 1; off < 16; off <<= 1) rs += __shfl_xor(rs, off, 16);
            lrow[r] = lrow[r] * alpha[r] + rs;
            mrow[r] = mn;
        }
        #pragma unroll
        for (int n = 0; n < 8; ++n)
            #pragma unroll
            for (int r = 0; r < 4; ++r) acc[n][r] *= alpha[r];
        // ---- P -> per-wave LDS (C-frag -> A-frag re-layout) ----
        {
            char* pb = smem + PB(w);
            #pragma unroll
            for (int r = 0; r < 4; ++r) {
                *(unsigned short*)(pb + (4 * g + r) * 80 + li * 2)        = f2bf(p0v[r]);
                *(unsigned short*)(pb + (4 * g + r) * 80 + (16 + li) * 2) = f2bf(p1v[r]);
            }
        }
        short8 pa = *(const short8*)(smem + PB(w) + li * 80 + g * 16);
        // ---- V B-fragments via hardware transpose read ----
        const unsigned vb0 = (unsigned)(size_t)(smem + VQ(b, kg)) + g * 256 + li * 8;
        short4v vt[16];
        #pragma unroll
        for (int h2 = 0; h2 < 8; ++h2) {
            vt[2 * h2]     = tr_read(vb0 + h2 * 1056);
            vt[2 * h2 + 1] = tr_read(vb0 + h2 * 1056 + 128);
        }
        asm volatile("s_waitcnt lgkmcnt(0)" ::: "memory");
        __builtin_amdgcn_sched_barrier(0);
        #pragma unroll
        for (int h2 = 0; h2 < 8; ++h2) {
            short8 vf = __builtin_shufflevector(vt[2 * h2], vt[2 * h2 + 1],
                                                0, 1, 2, 3, 4, 5, 6, 7);
            acc[h2] = __builtin_amdgcn_mfma_f32_16x16x32_bf16(pa, vf, acc[h2], 0, 0, 0);
        }
        __syncthreads();
    }

    // ---- cross-group merge (reuses KV LDS region; safe post-barrier) ----
    float* Ob = (float*)smem;                     // [4][64][128] f32
    float* ml = (float*)(smem + 131072);          // [4][64][2]  f32
    #pragma unroll
    for (int r = 0; r < 4; ++r) {
        const int row = qw * 16 + 4 * g + r;
        if (li == 0) {
            ml[(kg * 64 + row) * 2 + 0] = mrow[r];
            ml[(kg * 64 + row) * 2 + 1] = lrow[r];
        }
        #pragma unroll
        for (int n = 0; n < 8; ++n)
            Ob[kg * 8192 + row * 128 + 16 * n + li] = acc[n][r];
    }
    __syncthreads();
    {
        const int rr2 = tid >> 4;
        const int cb  = (tid & 15) * 8;
        float mg[4], lg[4];
        float mstar = -INFINITY;
        #pragma unroll
        for (int g2 = 0; g2 < 4; ++g2) {
            mg[g2] = ml[(g2 * 64 + rr2) * 2 + 0];
            lg[g2] = ml[(g2 * 64 + rr2) * 2 + 1];
            mstar = fmaxf(mstar, mg[g2]);
        }
        float cg[4], lstar = 0.f;
        #pragma unroll
        for (int g2 = 0; g2 < 4; ++g2) { cg[g2] = __expf(mg[g2] - mstar); lstar += lg[g2] * cg[g2]; }
        const float inv = 1.0f / lstar;
        float o[8] = {};
        #pragma unroll
        for (int g2 = 0; g2 < 4; ++g2) {
            f32x4 a = *(const f32x4*)&Ob[g2 * 8192 + rr2 * 128 + cb];
            f32x4 bq = *(const f32x4*)&Ob[g2 * 8192 + rr2 * 128 + cb + 4];
            o[0] += a[0] * cg[g2]; o[1] += a[1] * cg[g2];
            o[2] += a[2] * cg[g2]; o[3] += a[3] * cg[g2];
            o[4] += bq[0] * cg[g2]; o[5] += bq[1] * cg[g2];
            o[6] += bq[2] * cg[g2]; o[7] += bq[3] * cg[g2];
        }
        short8 o8;
        #pragma unroll
        for (int j = 0; j < 8; ++j) o8[j] = (short)f2bf(o[j] * inv);
        *(short8*)(aout + ((size_t)(q0 + rr2) * NH + head) * HD + cb) = o8;
    }
}

// ---------------------------------------------------------------------------
extern "C" void kernel_launch(void* const* d_in, const int* in_sizes, int n_in,
                              void* d_out, int out_size, void* d_ws, size_t ws_size,
                              hipStream_t stream) {
    const float* x_noise       = (const float*)d_in[0];
    const float* target_hidden = (const float*)d_in[1];
    const int*   noise_pos     = (const int*)d_in[2];
    const int*   ctx_pos       = (const int*)d_in[3];
    const float* in_k          = (const float*)d_in[4];
    const float* in_v          = (const float*)d_in[5];
    const int*   clp           = (const int*)d_in[6];
    const int*   acp           = (const int*)d_in[7];
    const float* Wq            = (const float*)d_in[8];
    const float* Wk            = (const float*)d_in[9];
    const float* Wv            = (const float*)d_in[10];
    const float* Wo            = (const float*)d_in[11];
    const float* q_scale       = (const float*)d_in[12];
    const float* k_scale       = (const float*)d_in[13];

    float* out   = (float*)d_out;
    float* out_k = out + (size_t)T_NOISE * D;
    float* out_v = out_k + (size_t)NH * MAX_KV * HD;

    float* ws     = (float*)d_ws;
    const size_t M1 = 1024u * 1024u;
    float* q_tmp  = ws;                          // [0, 2M) floats
    short* k_tmpb = (short*)(ws + 2 * M1);       // [2M, 3M)  2048x1024 bf16
    short* v_tmpb = (short*)(ws + 3 * M1);       // [3M, 4M)
    short* xbf    = (short*)(ws + 4 * M1);       // [4M, 6M)  2048x2048 bf16
    short* a_bf   = xbf;                         // overlay (xbf dead after KV GEMM)
    short* wq_t   = (short*)(ws + 6 * M1);       // [6M, 8M)
    short* wo_t   = wq_t;                        // overlay (wq_t dead after Q GEMM)
    short* wk_t   = (short*)(ws + 8 * M1);       // [8M, 9M)
    short* wv_t   = (short*)(ws + 9 * M1);       // [9M, 10M)
    short* kbf    = (short*)(ws + 10 * M1);      // [10M, 14M) 16x4096x128 bf16
    short* vbf    = (short*)(ws + 14 * M1);      // [14M, 18M)

    dim3 blk(256);
    cast_concat<<<2048, blk, 0, stream>>>(target_hidden, x_noise, xbf, 1024 * 2048);
    conv_transpose<<<dim3(32, 32), blk, 0, stream>>>(Wq, wq_t, 2048, 2048);
    gemm_bf16<<<dim3(16, 8), blk, 0, stream>>>(
        xbf + (size_t)1024 * 2048, wq_t, q_tmp, q_tmp, 2048, 2048, 2048, 1024);
    conv_transpose<<<dim3(16, 32), blk, 0, stream>>>(Wk, wk_t, 2048, 1024);
    conv_transpose<<<dim3(16, 32), blk, 0, stream>>>(Wv, wv_t, 2048, 1024);
    gemm_bf16_bo<<<dim3(16, 16), blk, 0, stream>>>(
        xbf, wk_t, k_tmpb, v_tmpb, 1024, 1024, 2048, 2048);
    conv_transpose<<<dim3(32, 32), blk, 0, stream>>>(Wo, wo_t, 2048, 2048);
    rmsrope<<<1024 * 16, 128, 0, stream>>>(q_tmp, NH, noise_pos, noise_pos, 2048, q_scale);
    rmsrope_bf<<<2048 * 8, 128, 0, stream>>>(k_tmpb, KHD, ctx_pos, noise_pos, 1024, k_scale);
    cache_scatter2<<<4096, blk, 0, stream>>>(in_k, in_v, k_tmpb, v_tmpb,
                                             out_k, out_v, kbf, vbf, clp, acp);
    attn_mfma<<<256, 1024, 0, stream>>>(q_tmp, kbf, vbf, a_bf, clp, acp);
    gemm_bf16<<<dim3(16, 8), blk, 0, stream>>>(
        a_bf, wo_t, out, out, 2048, 2048, 2048, 1024);
}

// Round 7
// 267.301 us; speedup vs baseline: 1.5521x; 1.1285x over previous
//
#include <hip/hip_runtime.h>
#include <hip/hip_bf16.h>
#include <math.h>

#define D 2048
#define NH 16
#define KHD 8
#define HD 128
#define T_NOISE 1024
#define T_PAD 1024
#define MAX_KV 4096
#define SM_SCALE 0.08838834764831845f  /* 1/sqrt(128) */

typedef __attribute__((ext_vector_type(8))) short short8;
typedef __attribute__((ext_vector_type(4))) short short4v;
typedef __attribute__((ext_vector_type(4))) float f32x4;

__device__ __forceinline__ unsigned short f2bf(float f) {
    union { float f; unsigned u; } v; v.f = f;
    unsigned r = v.u + 0x7fff + ((v.u >> 16) & 1);   // round-nearest-even
    return (unsigned short)(r >> 16);
}
__device__ __forceinline__ float bf2f(short s) {
    union { unsigned u; float f; } v; v.u = ((unsigned)(unsigned short)s) << 16;
    return v.f;
}
__device__ __forceinline__ void gload16(const void* g, void* l) {
    __builtin_amdgcn_global_load_lds(
        (const __attribute__((address_space(1))) unsigned int*)g,
        (__attribute__((address_space(3))) unsigned int*)l, 16, 0, 0);
}

// ---------------------------------------------------------------------------
// Concat + cast f32 -> bf16. (unchanged)
// ---------------------------------------------------------------------------
__global__ __launch_bounds__(256)
void cast_concat(const float* __restrict__ A0, const float* __restrict__ A1,
                 short* __restrict__ out, int splitElems) {
    int i = (blockIdx.x * 256 + threadIdx.x) * 8;
    const float* src = (i < splitElems) ? (A0 + i) : (A1 + (i - splitElems));
    float4 f0 = *(const float4*)src;
    float4 f1 = *(const float4*)(src + 4);
    short8 s;
    s[0] = (short)f2bf(f0.x); s[1] = (short)f2bf(f0.y);
    s[2] = (short)f2bf(f0.z); s[3] = (short)f2bf(f0.w);
    s[4] = (short)f2bf(f1.x); s[5] = (short)f2bf(f1.y);
    s[6] = (short)f2bf(f1.z); s[7] = (short)f2bf(f1.w);
    *(short8*)(out + i) = s;
}

// ---------------------------------------------------------------------------
// Convert + transpose: W f32 [R][C] -> Wt bf16 [C][R]. (unchanged)
// ---------------------------------------------------------------------------
__global__ __launch_bounds__(256)
void conv_transpose(const float* __restrict__ W, short* __restrict__ Wt,
                    int R, int C) {
    __shared__ short t[64][72];
    int tid = threadIdx.x;
    int r0 = blockIdx.y * 64, c0 = blockIdx.x * 64;
    int rl = tid >> 4, cl4 = (tid & 15) * 4;
    #pragma unroll
    for (int j = 0; j < 4; ++j) {
        int r = rl + j * 16;
        float4 f = *(const float4*)(W + (size_t)(r0 + r) * C + c0 + cl4);
        t[cl4 + 0][r] = (short)f2bf(f.x);
        t[cl4 + 1][r] = (short)f2bf(f.y);
        t[cl4 + 2][r] = (short)f2bf(f.z);
        t[cl4 + 3][r] = (short)f2bf(f.w);
    }
    __syncthreads();
    #pragma unroll
    for (int j = 0; j < 2; ++j) {
        int idx = tid + j * 256;
        int cr = idx >> 3, rc8 = (idx & 7) * 8;
        *(short8*)(Wt + (size_t)(c0 + cr) * R + r0 + rc8) = *(const short8*)&t[cr][rc8];
    }
}

// ---------------------------------------------------------------------------
// Fused QKV projection: one dispatch. Btp = [Wk_t | Wv_t | Wq_t] (4096 x 2048
// bf16, row n = output feature). KV region (n<2048): A = xbf (M=2048).
// Q region (n>=2048): A = xbf + 1024*2048 (noise rows), M=1024 (by<8 only).
// bf16 outputs: k_tmpb / v_tmpb / q_tmpb.
// ---------------------------------------------------------------------------
__global__ __launch_bounds__(256)
void gemm_qkv(const short* __restrict__ xbf, const short* __restrict__ Btp,
              short* __restrict__ k_tmpb, short* __restrict__ v_tmpb,
              short* __restrict__ q_tmpb) {
    const int n0 = blockIdx.x * 128;
    const int m0 = blockIdx.y * 128;
    const bool isQ = (n0 >= 2048);
    if (isQ && m0 >= 1024) return;
    const short* A = xbf + (isQ ? (size_t)1024 * 2048 : 0);

    __shared__ __align__(16) short As[128 * 32];
    __shared__ __align__(16) short Bs[128 * 32];
    const int tid = threadIdx.x;
    const int w = tid >> 6, lane = tid & 63;
    const int g = lane >> 4, li = lane & 15;
    const int wr = w >> 1, wc = w & 1;

    f32x4 acc[4][4];
    #pragma unroll
    for (int mi = 0; mi < 4; ++mi)
        #pragma unroll
        for (int ni = 0; ni < 4; ++ni) {
            acc[mi][ni][0] = 0.f; acc[mi][ni][1] = 0.f;
            acc[mi][ni][2] = 0.f; acc[mi][ni][3] = 0.f;
        }

    for (int k0 = 0; k0 < 2048; k0 += 32) {
        #pragma unroll
        for (int i = 0; i < 2; ++i) {
            int idx = i * 256 + w * 64 + lane;
            int row = idx >> 2, slot = idx & 3;
            gload16(A + (size_t)(m0 + row) * 2048 + k0 + slot * 8,
                    (char*)As + (size_t)(i * 256 + w * 64) * 16);
            gload16(Btp + (size_t)(n0 + row) * 2048 + k0 + slot * 8,
                    (char*)Bs + (size_t)(i * 256 + w * 64) * 16);
        }
        __syncthreads();
        short8 af[4], bf[4];
        #pragma unroll
        for (int mi = 0; mi < 4; ++mi)
            af[mi] = *(const short8*)&As[(wr * 64 + mi * 16 + li) * 32 + g * 8];
        #pragma unroll
        for (int ni = 0; ni < 4; ++ni)
            bf[ni] = *(const short8*)&Bs[(wc * 64 + ni * 16 + li) * 32 + g * 8];
        #pragma unroll
        for (int mi = 0; mi < 4; ++mi)
            #pragma unroll
            for (int ni = 0; ni < 4; ++ni)
                acc[mi][ni] = __builtin_amdgcn_mfma_f32_16x16x32_bf16(
                    af[mi], bf[ni], acc[mi][ni], 0, 0, 0);
        __syncthreads();
    }
    short* cp; int cbase, ldc2;
    if (n0 < 1024)      { cp = k_tmpb; cbase = 0;    ldc2 = 1024; }
    else if (n0 < 2048) { cp = v_tmpb; cbase = 1024; ldc2 = 1024; }
    else                { cp = q_tmpb; cbase = 2048; ldc2 = 2048; }
    #pragma unroll
    for (int mi = 0; mi < 4; ++mi)
        #pragma unroll
        for (int ni = 0; ni < 4; ++ni) {
            int n = n0 + wc * 64 + ni * 16 + li - cbase;
            #pragma unroll
            for (int r = 0; r < 4; ++r) {
                int m = m0 + wr * 64 + mi * 16 + 4 * g + r;
                cp[(size_t)m * ldc2 + n] = (short)f2bf(acc[mi][ni][r]);
            }
        }
}

// ---------------------------------------------------------------------------
// bf16 MFMA GEMM, f32 output (O projection). (unchanged, m97 structure)
// ---------------------------------------------------------------------------
__global__ __launch_bounds__(256)
void gemm_bf16(const short* __restrict__ A, const short* __restrict__ Bt,
               float* __restrict__ C0, float* __restrict__ C1,
               int csplit, int ldc, int K, int M) {
    __shared__ __align__(16) short As[128 * 32];
    __shared__ __align__(16) short Bs[128 * 32];
    const int tid = threadIdx.x;
    const int w = tid >> 6, lane = tid & 63;
    const int g = lane >> 4, li = lane & 15;
    const int wr = w >> 1, wc = w & 1;
    const int m0 = blockIdx.y * 128, n0 = blockIdx.x * 128;

    f32x4 acc[4][4];
    #pragma unroll
    for (int mi = 0; mi < 4; ++mi)
        #pragma unroll
        for (int ni = 0; ni < 4; ++ni) {
            acc[mi][ni][0] = 0.f; acc[mi][ni][1] = 0.f;
            acc[mi][ni][2] = 0.f; acc[mi][ni][3] = 0.f;
        }

    for (int k0 = 0; k0 < K; k0 += 32) {
        #pragma unroll
        for (int i = 0; i < 2; ++i) {
            int idx = i * 256 + w * 64 + lane;
            int row = idx >> 2, slot = idx & 3;
            gload16(A + (size_t)(m0 + row) * K + k0 + slot * 8,
                    (char*)As + (size_t)(i * 256 + w * 64) * 16);
            gload16(Bt + (size_t)(n0 + row) * K + k0 + slot * 8,
                    (char*)Bs + (size_t)(i * 256 + w * 64) * 16);
        }
        __syncthreads();
        short8 af[4], bf[4];
        #pragma unroll
        for (int mi = 0; mi < 4; ++mi)
            af[mi] = *(const short8*)&As[(wr * 64 + mi * 16 + li) * 32 + g * 8];
        #pragma unroll
        for (int ni = 0; ni < 4; ++ni)
            bf[ni] = *(const short8*)&Bs[(wc * 64 + ni * 16 + li) * 32 + g * 8];
        #pragma unroll
        for (int mi = 0; mi < 4; ++mi)
            #pragma unroll
            for (int ni = 0; ni < 4; ++ni)
                acc[mi][ni] = __builtin_amdgcn_mfma_f32_16x16x32_bf16(
                    af[mi], bf[ni], acc[mi][ni], 0, 0, 0);
        __syncthreads();
    }
    #pragma unroll
    for (int mi = 0; mi < 4; ++mi) {
        #pragma unroll
        for (int ni = 0; ni < 4; ++ni) {
            int n = n0 + wc * 64 + ni * 16 + li;
            float* cp; int cn;
            if (n < csplit) { cp = C0; cn = n; } else { cp = C1; cn = n - csplit; }
            #pragma unroll
            for (int r = 0; r < 4; ++r) {
                int m = m0 + wr * 64 + mi * 16 + 4 * g + r;
                cp[(size_t)m * ldc + cn] = acc[mi][ni][r];
            }
        }
    }
}

// ---------------------------------------------------------------------------
// Fused RMSNorm + RoPE, bf16 in-place, with post-multiplier (SM_SCALE fold).
// ---------------------------------------------------------------------------
__global__ __launch_bounds__(128)
void rmsrope_bf(short* __restrict__ x, int hpt,
                const int* __restrict__ posA, const int* __restrict__ posB,
                int splitT, const float* __restrict__ scale, float post) {
    __shared__ float red[128];
    __shared__ float nrm[128];
    int row = blockIdx.x;
    int h = threadIdx.x;
    float v = bf2f(x[(size_t)row * HD + h]);
    red[h] = v * v;
    __syncthreads();
    #pragma unroll
    for (int off = 64; off > 0; off >>= 1) {
        if (h < off) red[h] += red[h + off];
        __syncthreads();
    }
    float inv = rsqrtf(red[0] * (1.0f / 128.0f) + 1e-6f);
    nrm[h] = v * inv * scale[h];
    __syncthreads();
    if (h < 64) {
        int t = row / hpt;
        int pos = (t < splitT) ? posA[t] : posB[t - splitT];
        float inv_freq = expf((float)h * (-13.815510557964274f / 64.0f));
        float ang = (float)pos * inv_freq;
        float c = cosf(ang), s = sinf(ang);
        float x1 = nrm[h], x2 = nrm[h + 64];
        x[(size_t)row * HD + h]      = (short)f2bf((x1 * c - x2 * s) * post);
        x[(size_t)row * HD + h + 64] = (short)f2bf((x2 * c + x1 * s) * post);
    }
}

// ---------------------------------------------------------------------------
// Cache build: f32 output caches AND bf16 attention copies. (unchanged)
// ---------------------------------------------------------------------------
__global__ __launch_bounds__(256)
void cache_scatter2(const float* __restrict__ in_k, const float* __restrict__ in_v,
                    const short* __restrict__ k_tmpb, const short* __restrict__ v_tmpb,
                    float* __restrict__ out_k, float* __restrict__ out_v,
                    short* __restrict__ kbf, short* __restrict__ vbf,
                    const int* __restrict__ clp, const int* __restrict__ acp) {
    const int cache_len = clp[0], actx = acp[0];
    const int noise_start = cache_len + actx;
    const int new_len = noise_start + T_NOISE;
    int i = blockIdx.x * 256 + threadIdx.x;
    int n = i >> 16;
    int rem = i & 65535;
    int pos = rem >> 4;
    int h8 = (rem & 15) << 3;
    size_t co = ((size_t)(n * MAX_KV + pos)) * HD + h8;
    short8 ks8, vs8;
    if (pos >= cache_len && pos < new_len) {
        int tkn = (pos < noise_start) ? (pos - cache_len) : (T_PAD + (pos - noise_start));
        size_t so = ((size_t)(tkn * KHD + (n >> 1))) * HD + h8;
        ks8 = *(const short8*)(k_tmpb + so);
        vs8 = *(const short8*)(v_tmpb + so);
        float4 a, b;
        a.x = bf2f(ks8[0]); a.y = bf2f(ks8[1]); a.z = bf2f(ks8[2]); a.w = bf2f(ks8[3]);
        b.x = bf2f(ks8[4]); b.y = bf2f(ks8[5]); b.z = bf2f(ks8[6]); b.w = bf2f(ks8[7]);
        *(float4*)(out_k + co) = a; *(float4*)(out_k + co + 4) = b;
        a.x = bf2f(vs8[0]); a.y = bf2f(vs8[1]); a.z = bf2f(vs8[2]); a.w = bf2f(vs8[3]);
        b.x = bf2f(vs8[4]); b.y = bf2f(vs8[5]); b.z = bf2f(vs8[6]); b.w = bf2f(vs8[7]);
        *(float4*)(out_v + co) = a; *(float4*)(out_v + co + 4) = b;
    } else {
        float4 ka = *(const float4*)(in_k + co);
        float4 kb = *(const float4*)(in_k + co + 4);
        float4 va = *(const float4*)(in_v + co);
        float4 vb = *(const float4*)(in_v + co + 4);
        *(float4*)(out_k + co) = ka; *(float4*)(out_k + co + 4) = kb;
        *(float4*)(out_v + co) = va; *(float4*)(out_v + co + 4) = vb;
        ks8[0] = (short)f2bf(ka.x); ks8[1] = (short)f2bf(ka.y);
        ks8[2] = (short)f2bf(ka.z); ks8[3] = (short)f2bf(ka.w);
        ks8[4] = (short)f2bf(kb.x); ks8[5] = (short)f2bf(kb.y);
        ks8[6] = (short)f2bf(kb.z); ks8[7] = (short)f2bf(kb.w);
        vs8[0] = (short)f2bf(va.x); vs8[1] = (short)f2bf(va.y);
        vs8[2] = (short)f2bf(va.z); vs8[3] = (short)f2bf(va.w);
        vs8[4] = (short)f2bf(vb.x); vs8[5] = (short)f2bf(vb.y);
        vs8[6] = (short)f2bf(vb.z); vs8[7] = (short)f2bf(vb.w);
    }
    *(short8*)(kbf + co) = ks8;
    *(short8*)(vbf + co) = vs8;
}

// ---------------------------------------------------------------------------
// MFMA bf16 flash attention, 4 waves / block, KV split ACROSS blocks.
// Grid 1024 = 16 heads x 16 q-blocks x 4 KV-splits (4 blocks/CU).
// K fragments loaded DIRECTLY from L2-resident bf16 cache (no LDS).
// V double-buffered in LDS (tr-read subtile layout); P per-wave LDS.
// Each block writes partial (O, m, l); attn_merge combines the 4 splits.
// LDS = 2*8448 (V) + 4*1280 (P) = 22016 B.
// ---------------------------------------------------------------------------
#define VBUF(b) ((b) * 8448)
#define PBW(w) (16896 + (w) * 1280)

__device__ __forceinline__ short4v tr_read(unsigned addr) {
    short4v d;
    asm volatile("ds_read_b64_tr_b16 %0, %1" : "=v"(d) : "v"(addr));
    return d;
}

__global__ __launch_bounds__(256, 4)
void attn_mfma(const short* __restrict__ qbf, const short* __restrict__ kbf,
               const short* __restrict__ vbf, short* __restrict__ opA,
               short* __restrict__ opB, float* __restrict__ mlpart,
               const int* __restrict__ clp, const int* __restrict__ acp) {
    __shared__ __align__(16) char smem[22016];
    const int tid  = threadIdx.x;
    const int w    = tid >> 6;       // 0..3 = q sub-tile
    const int lane = tid & 63;
    const int g    = lane >> 4;
    const int li   = lane & 15;
    const int bid  = blockIdx.x;
    const int head = 2 * (bid & 7) + ((bid >> 3) & 1);   // XCD-clustered
    const int rest = bid >> 4;
    const int q0   = (rest & 15) * 64;
    const int kvs  = rest >> 4;      // 0..3 KV split
    const int new_len = clp[0] + acp[0] + T_NOISE;
    const int ntiles  = (new_len + 31) >> 5;
    const int ntq     = (ntiles + 3) >> 2;

    const short* kb_g = kbf + (size_t)head * MAX_KV * HD;
    const short* vb_g = vbf + (size_t)head * MAX_KV * HD;

    // Q A-fragments: direct bf16 loads (SM_SCALE pre-folded in rope)
    short8 qf[4];
    {
        const short* qp = qbf + ((size_t)(q0 + w * 16 + li) * NH + head) * HD;
        #pragma unroll
        for (int ks = 0; ks < 4; ++ks) qf[ks] = *(const short8*)(qp + 32 * ks + 8 * g);
    }

    f32x4 acc[8];
    #pragma unroll
    for (int n = 0; n < 8; ++n) { acc[n][0] = 0.f; acc[n][1] = 0.f; acc[n][2] = 0.f; acc[n][3] = 0.f; }
    float mrow[4], lrow[4];
    #pragma unroll
    for (int r = 0; r < 4; ++r) { mrow[r] = -INFINITY; lrow[r] = 0.f; }

    // V staging: wave w covers subtiles ht = 2w, 2w+1. Lane -> (row, colsub)
    // matched to gload_lds's linear dest (base + lane*16), m173 pattern.
    const int vrloc = 4 * (lane >> 3) + ((lane >> 1) & 3);
    const int vcof  = (lane & 1) * 8;

    auto STAGE = [&](int tt, int bb) {
        const int base = (kvs * ntq + tt) * 32;
        #pragma unroll
        for (int i2 = 0; i2 < 2; ++i2) {
            const int ht = w * 2 + i2;
            gload16(vb_g + ((size_t)(base + vrloc) << 7) + ht * 16 + vcof,
                    smem + VBUF(bb) + ht * 1056);
        }
    };

    STAGE(0, 0);
    __syncthreads();

    for (int t = 0; t < ntq; ++t) {
        const int b = t & 1;
        if (t + 1 < ntq) STAGE(t + 1, b ^ 1);   // async, overlaps compute
        // ---- QK^T: K fragments straight from global (L2-hit) ----
        const int pos0 = (kvs * ntq + t) << 5;
        f32x4 s0, s1;
        s0[0]=0.f; s0[1]=0.f; s0[2]=0.f; s0[3]=0.f; s1 = s0;
        {
            const short* kr0 = kb_g + ((size_t)(pos0 + li) << 7) + g * 8;
            const short* kr1 = kr0 + (16 << 7);
            #pragma unroll
            for (int ks = 0; ks < 4; ++ks) {
                short8 k0 = *(const short8*)(kr0 + ks * 32);
                short8 k1 = *(const short8*)(kr1 + ks * 32);
                s0 = __builtin_amdgcn_mfma_f32_16x16x32_bf16(qf[ks], k0, s0, 0, 0, 0);
                s1 = __builtin_amdgcn_mfma_f32_16x16x32_bf16(qf[ks], k1, s1, 0, 0, 0);
            }
        }
        if (pos0 + li >= new_len)      { s0[0] = -1e30f; s0[1] = -1e30f; s0[2] = -1e30f; s0[3] = -1e30f; }
        if (pos0 + li + 16 >= new_len) { s1[0] = -1e30f; s1[1] = -1e30f; s1[2] = -1e30f; s1[3] = -1e30f; }
        float p0v[4], p1v[4], alpha[4];
        #pragma unroll
        for (int r = 0; r < 4; ++r) {
            float mx = fmaxf(s0[r], s1[r]);
            #pragma unroll
            for (int off = 1; off < 16; off <<= 1) mx = fmaxf(mx, __shfl_xor(mx, off, 16));
            float mn = fmaxf(mrow[r], mx);
            alpha[r] = __expf(mrow[r] - mn);
            p0v[r] = __expf(s0[r] - mn);
            p1v[r] = __expf(s1[r] - mn);
            float rs = p0v[r] + p1v[r];
            #pragma unroll
            for (int off = 1; off < 16; off <<= 1) rs += __shfl_xor(rs, off, 16);
            lrow[r] = lrow[r] * alpha[r] + rs;
            mrow[r] = mn;
        }
        #pragma unroll
        for (int n = 0; n < 8; ++n)
            #pragma unroll
            for (int r = 0; r < 4; ++r) acc[n][r] *= alpha[r];
        // ---- P -> per-wave LDS (C-frag -> A-frag re-layout) ----
        {
            char* pb = smem + PBW(w);
            #pragma unroll
            for (int r = 0; r < 4; ++r) {
                *(unsigned short*)(pb + (4 * g + r) * 80 + li * 2)        = f2bf(p0v[r]);
                *(unsigned short*)(pb + (4 * g + r) * 80 + (16 + li) * 2) = f2bf(p1v[r]);
            }
        }
        short8 pa = *(const short8*)(smem + PBW(w) + li * 80 + g * 16);
        // ---- V B-fragments via hardware transpose read ----
        const unsigned vb0 = (unsigned)(size_t)(smem + VBUF(b)) + g * 256 + li * 8;
        short4v vt[16];
        #pragma unroll
        for (int h2 = 0; h2 < 8; ++h2) {
            vt[2 * h2]     = tr_read(vb0 + h2 * 1056);
            vt[2 * h2 + 1] = tr_read(vb0 + h2 * 1056 + 128);
        }
        asm volatile("s_waitcnt lgkmcnt(0)" ::: "memory");
        __builtin_amdgcn_sched_barrier(0);
        #pragma unroll
        for (int h2 = 0; h2 < 8; ++h2) {
            short8 vf = __builtin_shufflevector(vt[2 * h2], vt[2 * h2 + 1],
                                                0, 1, 2, 3, 4, 5, 6, 7);
            acc[h2] = __builtin_amdgcn_mfma_f32_16x16x32_bf16(pa, vf, acc[h2], 0, 0, 0);
        }
        __syncthreads();   // drains trV reads + next-tile stage (vmcnt) together
    }

    // ---- write partial O (unnormalized), m, l ----
    short* op = (kvs < 2) ? (opA + (size_t)kvs * 16 * 1024 * 128)
                          : (opB + (size_t)(kvs - 2) * 16 * 1024 * 128);
    #pragma unroll
    for (int r = 0; r < 4; ++r) {
        const int row = q0 + w * 16 + 4 * g + r;
        const size_t ro = ((size_t)(head << 10) + row) * 128;
        #pragma unroll
        for (int n = 0; n < 8; ++n)
            op[ro + 16 * n + li] = (short)f2bf(acc[n][r]);
        if (li == 0) {
            float* ml = mlpart + (((size_t)(kvs * 16 + head) << 10) + row) * 2;
            ml[0] = mrow[r]; ml[1] = lrow[r];
        }
    }
}

// ---------------------------------------------------------------------------
// Merge the 4 KV-split partials -> a_bf (bf16 [q][head*128+c]).
// ---------------------------------------------------------------------------
__global__ __launch_bounds__(256)
void attn_merge(const short* __restrict__ opA, const short* __restrict__ opB,
                const float* __restrict__ mlpart, short* __restrict__ a_bf) {
    int gid = blockIdx.x * 256 + threadIdx.x;
    int row = gid >> 4;                 // 0..16383
    int c8  = (gid & 15) * 8;
    int head = row >> 10, q = row & 1023;
    float mg[4], lg[4], mstar = -INFINITY;
    #pragma unroll
    for (int s = 0; s < 4; ++s) {
        const float* ml = mlpart + (((size_t)(s * 16 + head) << 10) + q) * 2;
        mg[s] = ml[0]; lg[s] = ml[1];
        mstar = fmaxf(mstar, mg[s]);
    }
    float cg[4], lstar = 0.f;
    #pragma unroll
    for (int s = 0; s < 4; ++s) { cg[s] = __expf(mg[s] - mstar); lstar += lg[s] * cg[s]; }
    const float inv = 1.0f / lstar;
    float o[8] = {};
    #pragma unroll
    for (int s = 0; s < 4; ++s) {
        const short* op = (s < 2) ? (opA + (size_t)s * 16 * 1024 * 128)
                                  : (opB + (size_t)(s - 2) * 16 * 1024 * 128);
        short8 v = *(const short8*)(op + (((size_t)(head << 10)) + q) * 128 + c8);
        #pragma unroll
        for (int j = 0; j < 8; ++j) o[j] += cg[s] * bf2f(v[j]);
    }
    short8 o8;
    #pragma unroll
    for (int j = 0; j < 8; ++j) o8[j] = (short)f2bf(o[j] * inv);
    *(short8*)(a_bf + (size_t)q * 2048 + head * 128 + c8) = o8;
}

// ---------------------------------------------------------------------------
extern "C" void kernel_launch(void* const* d_in, const int* in_sizes, int n_in,
                              void* d_out, int out_size, void* d_ws, size_t ws_size,
                              hipStream_t stream) {
    const float* x_noise       = (const float*)d_in[0];
    const float* target_hidden = (const float*)d_in[1];
    const int*   noise_pos     = (const int*)d_in[2];
    const int*   ctx_pos       = (const int*)d_in[3];
    const float* in_k          = (const float*)d_in[4];
    const float* in_v          = (const float*)d_in[5];
    const int*   clp           = (const int*)d_in[6];
    const int*   acp           = (const int*)d_in[7];
    const float* Wq            = (const float*)d_in[8];
    const float* Wk            = (const float*)d_in[9];
    const float* Wv            = (const float*)d_in[10];
    const float* Wo            = (const float*)d_in[11];
    const float* q_scale       = (const float*)d_in[12];
    const float* k_scale       = (const float*)d_in[13];

    float* out   = (float*)d_out;
    float* out_k = out + (size_t)T_NOISE * D;
    float* out_v = out_k + (size_t)NH * MAX_KV * HD;

    float* ws     = (float*)d_ws;
    const size_t M1 = 1024u * 1024u;
    short* q_tmpb = (short*)ws;                   // [0,1M) fl = 2M bf16
    short* a_bf   = q_tmpb;                       // overlay (q dead after attn)
    short* k_tmpb = (short*)(ws + 1 * M1);        // [1M,2M)
    short* v_tmpb = (short*)(ws + 2 * M1);        // [2M,3M)
    float* mlpart = (float*)v_tmpb;               // overlay (v_tmpb dead after scatter)
    short* xbf    = (short*)(ws + 3 * M1);        // [3M,5M)
    short* opartA = xbf;                          // overlay (xbf dead after gemm_qkv)
    short* btpack = (short*)(ws + 5 * M1);        // [5M,9M) 4096x2048 bf16
    short* wo_t   = btpack;                       // overlay rows 0..2047 post-QKV
    short* opartB = (short*)(ws + 7 * M1);        // overlay btpack rows 2048.. (Wq, dead)
    short* kbf    = (short*)(ws + 9 * M1);        // [9M,13M)
    short* vbf    = (short*)(ws + 13 * M1);       // [13M,17M)

    dim3 blk(256);
    cast_concat<<<2048, blk, 0, stream>>>(target_hidden, x_noise, xbf, 1024 * 2048);
    conv_transpose<<<dim3(16, 32), blk, 0, stream>>>(Wk, btpack, 2048, 1024);
    conv_transpose<<<dim3(16, 32), blk, 0, stream>>>(Wv, btpack + (size_t)1024 * 2048, 2048, 1024);
    conv_transpose<<<dim3(32, 32), blk, 0, stream>>>(Wq, btpack + (size_t)2048 * 2048, 2048, 2048);
    gemm_qkv<<<dim3(32, 16), blk, 0, stream>>>(xbf, btpack, k_tmpb, v_tmpb, q_tmpb);
    conv_transpose<<<dim3(32, 32), blk, 0, stream>>>(Wo, wo_t, 2048, 2048);
    rmsrope_bf<<<1024 * 16, 128, 0, stream>>>(q_tmpb, NH, noise_pos, noise_pos, 2048,
                                              q_scale, SM_SCALE);
    rmsrope_bf<<<2048 * 8, 128, 0, stream>>>(k_tmpb, KHD, ctx_pos, noise_pos, 1024,
                                             k_scale, 1.0f);
    cache_scatter2<<<4096, blk, 0, stream>>>(in_k, in_v, k_tmpb, v_tmpb,
                                             out_k, out_v, kbf, vbf, clp, acp);
    attn_mfma<<<1024, blk, 0, stream>>>(q_tmpb, kbf, vbf, opartA, opartB, mlpart, clp, acp);
    attn_merge<<<1024, blk, 0, stream>>>(opartA, opartB, mlpart, a_bf);
    gemm_bf16<<<dim3(16, 8), blk, 0, stream>>>(
        a_bf, wo_t, out, out, 2048, 2048, 2048, 1024);
}